// Round 1
// baseline (3110.008 us; speedup 1.0000x reference)
//
#include <hip/hip_runtime.h>
#include <math.h>

static inline size_t align256(size_t x) { return (x + 255) & ~(size_t)255; }

// ---------------- degree / norm ----------------
__global__ __launch_bounds__(256) void k_deg_init(int* __restrict__ deg, int n) {
  int i = blockIdx.x * 256 + threadIdx.x;
  if (i < n) deg[i] = 1;   // self-loop
}

__global__ __launch_bounds__(256) void k_deg_count(const int* __restrict__ dst,
                                                   int* __restrict__ deg, int E) {
  int e = blockIdx.x * 256 + threadIdx.x;
  if (e < E) atomicAdd(&deg[dst[e]], 1);
}

__global__ __launch_bounds__(256) void k_dinv(const int* __restrict__ deg,
                                              float* __restrict__ dinv, int n) {
  int i = blockIdx.x * 256 + threadIdx.x;
  if (i < n) dinv[i] = rsqrtf((float)deg[i]);
}

// ---------------- agg init: agg = bias + dinv^2 * xw (self-loop term) ----------------
__global__ __launch_bounds__(256) void k_selfinit(const float* __restrict__ xw,
                                                  const float* __restrict__ dinv,
                                                  const float* __restrict__ bias,
                                                  float* __restrict__ agg, int n) {
  int idx = blockIdx.x * 256 + threadIdx.x;
  if (idx >= n * 32) return;
  int i = idx >> 5;
  int c = (idx & 31) << 2;
  float di = dinv[i];
  float s = di * di;
  const float4 v = *(const float4*)(xw + (size_t)i * 128 + c);
  const float4 b = *(const float4*)(bias + c);
  float4 o;
  o.x = fmaf(s, v.x, b.x);
  o.y = fmaf(s, v.y, b.y);
  o.z = fmaf(s, v.z, b.z);
  o.w = fmaf(s, v.w, b.w);
  *(float4*)(agg + (size_t)i * 128 + c) = o;
}

// ---------------- edge scatter: agg[d] += dinv[s]*dinv[d] * xw[s] ----------------
__global__ __launch_bounds__(256) void k_scatter(const int* __restrict__ src,
                                                 const int* __restrict__ dst,
                                                 const float* __restrict__ dinv,
                                                 const float* __restrict__ xw,
                                                 float* __restrict__ agg, int E) {
  int lane = threadIdx.x & 63;
  int e = (blockIdx.x * 256 + threadIdx.x) >> 6;   // wave per edge
  if (e >= E) return;
  int s = src[e], d = dst[e];
  float nrm = dinv[s] * dinv[d];
  const float2 v = *(const float2*)(xw + (size_t)s * 128 + lane * 2);
  float* base = agg + (size_t)d * 128 + lane * 2;
  atomicAdd(base, v.x * nrm);
  atomicAdd(base + 1, v.y * nrm);
}

// ---------------- GEMM: C[n x 128] = (RELU_A ? relu(A) : A) @ W(128x128) (+bias, relu) ----------------
// 64x64 tile, 4x4 micro-tile, 256 threads.
template<bool RELU_A, bool BIAS_RELU>
__global__ __launch_bounds__(256) void k_gemm(const float* __restrict__ A,
                                              const float* __restrict__ W,
                                              const float* __restrict__ bias,
                                              float* __restrict__ C, int n) {
  __shared__ float As[64][132];   // pad: stride 132 floats (528B, 16B-aligned)
  __shared__ float Ws[128][68];   // pad: stride 68 floats (272B, 16B-aligned)
  const int tid = threadIdx.x;
  const int ct = blockIdx.x;                 // column tile 0/1
  const size_t row0 = (size_t)blockIdx.y * 64;

  // stage W tile (128 x 64)
  {
    int c = (tid & 15) << 2;
    int kb = tid >> 4;
#pragma unroll
    for (int p = 0; p < 8; ++p) {
      int k = kb + p * 16;
      const float4 wv = *(const float4*)(W + (size_t)k * 128 + ct * 64 + c);
      *(float4*)&Ws[k][c] = wv;
    }
  }
  // stage A tile (64 x 128)
  {
    int c = (tid & 31) << 2;
    int rb = tid >> 5;
#pragma unroll
    for (int p = 0; p < 8; ++p) {
      int r = rb + p * 8;
      size_t gr = row0 + r;
      float4 av = make_float4(0.f, 0.f, 0.f, 0.f);
      if (gr < (size_t)n) {
        av = *(const float4*)(A + gr * 128 + c);
        if (RELU_A) {
          av.x = fmaxf(av.x, 0.f);
          av.y = fmaxf(av.y, 0.f);
          av.z = fmaxf(av.z, 0.f);
          av.w = fmaxf(av.w, 0.f);
        }
      }
      *(float4*)&As[r][c] = av;
    }
  }
  __syncthreads();

  const int tx = tid & 15, ty = tid >> 4;
  const int r0 = ty << 2, c0 = tx << 2;
  float acc[4][4] = {{0.f}};

#pragma unroll 4
  for (int k = 0; k < 128; ++k) {
    const float4 wv = *(const float4*)&Ws[k][c0];
    float a[4];
#pragma unroll
    for (int i = 0; i < 4; ++i) a[i] = As[r0 + i][k];
#pragma unroll
    for (int i = 0; i < 4; ++i) {
      acc[i][0] = fmaf(a[i], wv.x, acc[i][0]);
      acc[i][1] = fmaf(a[i], wv.y, acc[i][1]);
      acc[i][2] = fmaf(a[i], wv.z, acc[i][2]);
      acc[i][3] = fmaf(a[i], wv.w, acc[i][3]);
    }
  }

  float bvv[4] = {0.f, 0.f, 0.f, 0.f};
  if (BIAS_RELU) {
    const float4 bv = *(const float4*)(bias + ct * 64 + c0);
    bvv[0] = bv.x; bvv[1] = bv.y; bvv[2] = bv.z; bvv[3] = bv.w;
  }
#pragma unroll
  for (int i = 0; i < 4; ++i) {
    size_t gr = row0 + r0 + i;
    if (gr < (size_t)n) {
      float4 o;
      o.x = acc[i][0]; o.y = acc[i][1]; o.z = acc[i][2]; o.w = acc[i][3];
      if (BIAS_RELU) {
        o.x = fmaxf(o.x + bvv[0], 0.f);
        o.y = fmaxf(o.y + bvv[1], 0.f);
        o.z = fmaxf(o.z + bvv[2], 0.f);
        o.w = fmaxf(o.w + bvv[3], 0.f);
      }
      *(float4*)(C + gr * 128 + ct * 64 + c0) = o;
    }
  }
}

// ---------------- dot: out[i] = H[i,:] . w  (wave per node) ----------------
__global__ __launch_bounds__(256) void k_dot(const float* __restrict__ H,
                                             const float* __restrict__ w,
                                             float* __restrict__ out, int n) {
  int lane = threadIdx.x & 63;
  int i = (blockIdx.x * 256 + threadIdx.x) >> 6;
  if (i >= n) return;
  const float* h = H + (size_t)i * 128;
  float v = h[lane] * w[lane] + h[lane + 64] * w[lane + 64];
#pragma unroll
  for (int off = 32; off; off >>= 1) v += __shfl_down(v, off, 64);
  if (lane == 0) out[i] = v;
}

// ---------------- final: p1 = sigmoid(relu(rep).Wpp + bpp); y = select ----------------
__global__ __launch_bounds__(256) void k_final(const float* __restrict__ rep_pre,  // pre-relu agg2
                                               const float* __restrict__ Wpp,
                                               const float* __restrict__ bpp,
                                               const float* __restrict__ y0a,
                                               const float* __restrict__ y1a,
                                               const float* __restrict__ b01,
                                               const float* __restrict__ b11,
                                               const int* __restrict__ t,
                                               float* __restrict__ out, int n) {
  int lane = threadIdx.x & 63;
  int i = (blockIdx.x * 256 + threadIdx.x) >> 6;
  if (i >= n) return;
  const float* r = rep_pre + (size_t)i * 128;
  float r1 = fmaxf(r[lane], 0.f);
  float r2 = fmaxf(r[lane + 64], 0.f);
  float v = r1 * Wpp[lane] + r2 * Wpp[lane + 64];
#pragma unroll
  for (int off = 32; off; off >>= 1) v += __shfl_down(v, off, 64);
  if (lane == 0) {
    float p = 1.f / (1.f + expf(-(v + bpp[0])));
    out[i] = p;
    out[n + i] = (t[i] > 0) ? (y1a[i] + b11[0]) : (y0a[i] + b01[0]);
  }
}

extern "C" void kernel_launch(void* const* d_in, const int* in_sizes, int n_in,
                              void* d_out, int out_size, void* d_ws, size_t ws_size,
                              hipStream_t stream) {
  const float* x   = (const float*)d_in[0];
  const int*   t   = (const int*)d_in[1];
  const int*   ei  = (const int*)d_in[3];
  const float* W1  = (const float*)d_in[4];
  const float* b1  = (const float*)d_in[5];
  const float* W2  = (const float*)d_in[6];
  const float* b2  = (const float*)d_in[7];
  const float* W00 = (const float*)d_in[8];
  const float* b00 = (const float*)d_in[9];
  const float* W10 = (const float*)d_in[10];
  const float* b10 = (const float*)d_in[11];
  const float* W01 = (const float*)d_in[12];
  const float* b01 = (const float*)d_in[13];
  const float* W11 = (const float*)d_in[14];
  const float* b11 = (const float*)d_in[15];
  const float* Wpp = (const float*)d_in[16];
  const float* bpp = (const float*)d_in[17];

  const int N = in_sizes[0] / 128;
  const int E = in_sizes[3] / 2;
  const int* srcp = ei;
  const int* dstp = ei + E;

  char* ws = (char*)d_ws;
  const size_t S = (size_t)N * 128 * sizeof(float);
  float* B1  = (float*)ws; ws += align256(S);
  float* B2  = (float*)ws; ws += align256(S);
  int*   deg = (int*)ws;   ws += align256((size_t)N * 4);
  float* dnv = (float*)ws; ws += align256((size_t)N * 4);
  float* y0a = (float*)ws; ws += align256((size_t)N * 4);
  float* y1a = (float*)ws; ws += align256((size_t)N * 4);
  float* out = (float*)d_out;

  const int nbN = (N + 255) / 256;
  const int nbE = (E + 255) / 256;
  const int nbNode32 = (N * 32 + 255) / 256;
  const int nbWaveN = (N + 3) / 4;                       // wave per node
  const int nbWaveE = (int)(((size_t)E * 64 + 255) / 256);  // wave per edge
  dim3 gemmGrid(2, (N + 63) / 64);

  // degrees + normalization
  k_deg_init<<<nbN, 256, 0, stream>>>(deg, N);
  k_deg_count<<<nbE, 256, 0, stream>>>(dstp, deg, E);
  k_dinv<<<nbN, 256, 0, stream>>>(deg, dnv, N);

  // layer 1: xw1 = x@W1 -> B1 ; agg1 -> B2 (init b1 + self, scatter edges)
  k_gemm<false, false><<<gemmGrid, 256, 0, stream>>>(x, W1, nullptr, B1, N);
  k_selfinit<<<nbNode32, 256, 0, stream>>>(B1, dnv, b1, B2, N);
  k_scatter<<<nbWaveE, 256, 0, stream>>>(srcp, dstp, dnv, B1, B2, E);

  // layer 2: xw2 = relu(agg1)@W2 -> B1 ; agg2 -> B2
  k_gemm<true, false><<<gemmGrid, 256, 0, stream>>>(B2, W2, nullptr, B1, N);
  k_selfinit<<<nbNode32, 256, 0, stream>>>(B1, dnv, b2, B2, N);
  k_scatter<<<nbWaveE, 256, 0, stream>>>(srcp, dstp, dnv, B1, B2, E);

  // heads: rep = relu(B2) applied at A-load
  k_gemm<true, true><<<gemmGrid, 256, 0, stream>>>(B2, W00, b00, B1, N);
  k_dot<<<nbWaveN, 256, 0, stream>>>(B1, W01, y0a, N);
  k_gemm<true, true><<<gemmGrid, 256, 0, stream>>>(B2, W10, b10, B1, N);
  k_dot<<<nbWaveN, 256, 0, stream>>>(B1, W11, y1a, N);

  k_final<<<nbWaveN, 256, 0, stream>>>(B2, Wpp, bpp, y0a, y1a, b01, b11, t, out, N);
}

// Round 4
// 826.601 us; speedup vs baseline: 3.7624x; 3.7624x over previous
//
#include <hip/hip_runtime.h>
#include <math.h>

static inline size_t align256(size_t x) { return (x + 255) & ~(size_t)255; }

// ---------------- degree ----------------
__global__ __launch_bounds__(256) void k_deg_zero(int* __restrict__ deg, int n) {
  int i = blockIdx.x * 256 + threadIdx.x;
  if (i < n) deg[i] = 0;
}

__global__ __launch_bounds__(256) void k_deg_count(const int* __restrict__ dst,
                                                   int* __restrict__ deg, int E) {
  int e = blockIdx.x * 256 + threadIdx.x;
  if (e < E) atomicAdd(&deg[dst[e]], 1);
}

// dinv = rsqrt(indeg + 1)  (self-loop)
__global__ __launch_bounds__(256) void k_dinv(const int* __restrict__ deg,
                                              float* __restrict__ dinv, int n) {
  int i = blockIdx.x * 256 + threadIdx.x;
  if (i < n) dinv[i] = rsqrtf((float)(deg[i] + 1));
}

// ---------------- exclusive scan (3 kernels) ----------------
__global__ __launch_bounds__(256) void k_scan1(const int* __restrict__ deg,
                                               int* __restrict__ excl,
                                               int* __restrict__ blksum, int n) {
  __shared__ int sm[256];
  int i = blockIdx.x * 256 + threadIdx.x;
  int v = (i < n) ? deg[i] : 0;
  sm[threadIdx.x] = v;
  __syncthreads();
  for (int off = 1; off < 256; off <<= 1) {
    int t = (threadIdx.x >= off) ? sm[threadIdx.x - off] : 0;
    __syncthreads();
    sm[threadIdx.x] += t;
    __syncthreads();
  }
  if (i < n) excl[i] = sm[threadIdx.x] - v;   // exclusive within block
  if (threadIdx.x == 255) blksum[blockIdx.x] = sm[255];
}

__global__ __launch_bounds__(1024) void k_scan2(int* __restrict__ blksum, int nb) {
  __shared__ int sm[1024];
  int v = (threadIdx.x < (unsigned)nb) ? blksum[threadIdx.x] : 0;
  sm[threadIdx.x] = v;
  __syncthreads();
  for (int off = 1; off < 1024; off <<= 1) {
    int t = (threadIdx.x >= off) ? sm[threadIdx.x - off] : 0;
    __syncthreads();
    sm[threadIdx.x] += t;
    __syncthreads();
  }
  if (threadIdx.x < (unsigned)nb) blksum[threadIdx.x] = sm[threadIdx.x] - v;  // exclusive
}

__global__ __launch_bounds__(256) void k_scan3(int* __restrict__ excl,
                                               const int* __restrict__ blksum,
                                               int* __restrict__ cursor, int n) {
  int i = blockIdx.x * 256 + threadIdx.x;
  if (i < n) {
    int r = excl[i] + blksum[blockIdx.x];
    excl[i] = r;
    cursor[i] = r;
  }
}

// ---------------- CSR fill: srcs + per-edge norm ----------------
__global__ __launch_bounds__(256) void k_fill(const int* __restrict__ src,
                                              const int* __restrict__ dst,
                                              const float* __restrict__ dinv,
                                              int* __restrict__ cursor,
                                              int* __restrict__ srcs,
                                              float* __restrict__ nrms, int E) {
  int e = blockIdx.x * 256 + threadIdx.x;
  if (e >= E) return;
  int s = src[e], d = dst[e];
  int pos = atomicAdd(&cursor[d], 1);
  srcs[pos] = s;
  nrms[pos] = dinv[s] * dinv[d];
}

// ---------------- gather-aggregate: wave per dst node ----------------
// out[i] = bias + dinv[i]^2 * xw[i] + sum_j nrm_j * xw[src_j]
__global__ __launch_bounds__(256) void k_gather(const int* __restrict__ srcs,
                                                const float* __restrict__ nrms,
                                                const int* __restrict__ rowptr,
                                                const int* __restrict__ deg,
                                                const float* __restrict__ dinv,
                                                const float* __restrict__ xw,
                                                const float* __restrict__ bias,
                                                float* __restrict__ out, int n) {
  int lane = threadIdx.x & 63;
  int i = (blockIdx.x * 256 + threadIdx.x) >> 6;
  if (i >= n) return;
  const int c = lane * 2;
  float di = dinv[i];
  float s2 = di * di;
  const float2 self = *(const float2*)(xw + (size_t)i * 128 + c);
  const float2 bv = *(const float2*)(bias + c);
  float ax = fmaf(s2, self.x, bv.x);
  float ay = fmaf(s2, self.y, bv.y);

  int j = rowptr[i];
  int end = j + deg[i];
  for (; j + 4 <= end; j += 4) {
    int s0 = srcs[j], s1 = srcs[j + 1], s2i = srcs[j + 2], s3 = srcs[j + 3];
    float n0 = nrms[j], n1 = nrms[j + 1], n2 = nrms[j + 2], n3 = nrms[j + 3];
    const float2 v0 = *(const float2*)(xw + (size_t)s0 * 128 + c);
    const float2 v1 = *(const float2*)(xw + (size_t)s1 * 128 + c);
    const float2 v2 = *(const float2*)(xw + (size_t)s2i * 128 + c);
    const float2 v3 = *(const float2*)(xw + (size_t)s3 * 128 + c);
    ax = fmaf(v0.x, n0, ax); ay = fmaf(v0.y, n0, ay);
    ax = fmaf(v1.x, n1, ax); ay = fmaf(v1.y, n1, ay);
    ax = fmaf(v2.x, n2, ax); ay = fmaf(v2.y, n2, ay);
    ax = fmaf(v3.x, n3, ax); ay = fmaf(v3.y, n3, ay);
  }
  for (; j < end; ++j) {
    int s = srcs[j];
    float nm = nrms[j];
    const float2 v = *(const float2*)(xw + (size_t)s * 128 + c);
    ax = fmaf(v.x, nm, ax); ay = fmaf(v.y, nm, ay);
  }
  float2 o; o.x = ax; o.y = ay;
  *(float2*)(out + (size_t)i * 128 + c) = o;
}

// ---------------- legacy atomic path (fallback if ws too small) ----------------
__global__ __launch_bounds__(256) void k_deg_init1(int* __restrict__ deg, int n) {
  int i = blockIdx.x * 256 + threadIdx.x;
  if (i < n) deg[i] = 1;
}
__global__ __launch_bounds__(256) void k_dinv0(const int* __restrict__ deg,
                                               float* __restrict__ dinv, int n) {
  int i = blockIdx.x * 256 + threadIdx.x;
  if (i < n) dinv[i] = rsqrtf((float)deg[i]);
}
__global__ __launch_bounds__(256) void k_selfinit(const float* __restrict__ xw,
                                                  const float* __restrict__ dinv,
                                                  const float* __restrict__ bias,
                                                  float* __restrict__ agg, int n) {
  int idx = blockIdx.x * 256 + threadIdx.x;
  if (idx >= n * 32) return;
  int i = idx >> 5;
  int c = (idx & 31) << 2;
  float di = dinv[i];
  float s = di * di;
  const float4 v = *(const float4*)(xw + (size_t)i * 128 + c);
  const float4 b = *(const float4*)(bias + c);
  float4 o;
  o.x = fmaf(s, v.x, b.x);
  o.y = fmaf(s, v.y, b.y);
  o.z = fmaf(s, v.z, b.z);
  o.w = fmaf(s, v.w, b.w);
  *(float4*)(agg + (size_t)i * 128 + c) = o;
}
__global__ __launch_bounds__(256) void k_scatter(const int* __restrict__ src,
                                                 const int* __restrict__ dst,
                                                 const float* __restrict__ dinv,
                                                 const float* __restrict__ xw,
                                                 float* __restrict__ agg, int E) {
  int lane = threadIdx.x & 63;
  int e = (blockIdx.x * 256 + threadIdx.x) >> 6;
  if (e >= E) return;
  int s = src[e], d = dst[e];
  float nrm = dinv[s] * dinv[d];
  const float2 v = *(const float2*)(xw + (size_t)s * 128 + lane * 2);
  float* base = agg + (size_t)d * 128 + lane * 2;
  atomicAdd(base, v.x * nrm);
  atomicAdd(base + 1, v.y * nrm);
}

// ---------------- GEMM: C = (RELU_A ? relu(A) : A) @ W (+bias, relu) ----------------
template<bool RELU_A, bool BIAS_RELU>
__global__ __launch_bounds__(256) void k_gemm(const float* __restrict__ A,
                                              const float* __restrict__ W,
                                              const float* __restrict__ bias,
                                              float* __restrict__ C, int n) {
  __shared__ float As[64][132];
  __shared__ float Ws[128][68];
  const int tid = threadIdx.x;
  const int ct = blockIdx.x;
  const size_t row0 = (size_t)blockIdx.y * 64;

  {
    int c = (tid & 15) << 2;
    int kb = tid >> 4;
#pragma unroll
    for (int p = 0; p < 8; ++p) {
      int k = kb + p * 16;
      const float4 wv = *(const float4*)(W + (size_t)k * 128 + ct * 64 + c);
      *(float4*)&Ws[k][c] = wv;
    }
  }
  {
    int c = (tid & 31) << 2;
    int rb = tid >> 5;
#pragma unroll
    for (int p = 0; p < 8; ++p) {
      int r = rb + p * 8;
      size_t gr = row0 + r;
      float4 av = make_float4(0.f, 0.f, 0.f, 0.f);
      if (gr < (size_t)n) {
        av = *(const float4*)(A + gr * 128 + c);
        if (RELU_A) {
          av.x = fmaxf(av.x, 0.f);
          av.y = fmaxf(av.y, 0.f);
          av.z = fmaxf(av.z, 0.f);
          av.w = fmaxf(av.w, 0.f);
        }
      }
      *(float4*)&As[r][c] = av;
    }
  }
  __syncthreads();

  const int tx = tid & 15, ty = tid >> 4;
  const int r0 = ty << 2, c0 = tx << 2;
  float acc[4][4] = {{0.f}};

#pragma unroll 4
  for (int k = 0; k < 128; ++k) {
    const float4 wv = *(const float4*)&Ws[k][c0];
    float a[4];
#pragma unroll
    for (int i = 0; i < 4; ++i) a[i] = As[r0 + i][k];
#pragma unroll
    for (int i = 0; i < 4; ++i) {
      acc[i][0] = fmaf(a[i], wv.x, acc[i][0]);
      acc[i][1] = fmaf(a[i], wv.y, acc[i][1]);
      acc[i][2] = fmaf(a[i], wv.z, acc[i][2]);
      acc[i][3] = fmaf(a[i], wv.w, acc[i][3]);
    }
  }

  float bvv[4] = {0.f, 0.f, 0.f, 0.f};
  if (BIAS_RELU) {
    const float4 bv = *(const float4*)(bias + ct * 64 + c0);
    bvv[0] = bv.x; bvv[1] = bv.y; bvv[2] = bv.z; bvv[3] = bv.w;
  }
#pragma unroll
  for (int i = 0; i < 4; ++i) {
    size_t gr = row0 + r0 + i;
    if (gr < (size_t)n) {
      float4 o;
      o.x = acc[i][0]; o.y = acc[i][1]; o.z = acc[i][2]; o.w = acc[i][3];
      if (BIAS_RELU) {
        o.x = fmaxf(o.x + bvv[0], 0.f);
        o.y = fmaxf(o.y + bvv[1], 0.f);
        o.z = fmaxf(o.z + bvv[2], 0.f);
        o.w = fmaxf(o.w + bvv[3], 0.f);
      }
      *(float4*)(C + gr * 128 + ct * 64 + c0) = o;
    }
  }
}

// ---------------- dot: out[i] = H[i,:] . w ----------------
__global__ __launch_bounds__(256) void k_dot(const float* __restrict__ H,
                                             const float* __restrict__ w,
                                             float* __restrict__ out, int n) {
  int lane = threadIdx.x & 63;
  int i = (blockIdx.x * 256 + threadIdx.x) >> 6;
  if (i >= n) return;
  const float* h = H + (size_t)i * 128;
  float v = h[lane] * w[lane] + h[lane + 64] * w[lane + 64];
#pragma unroll
  for (int off = 32; off; off >>= 1) v += __shfl_down(v, off, 64);
  if (lane == 0) out[i] = v;
}

// ---------------- final ----------------
__global__ __launch_bounds__(256) void k_final(const float* __restrict__ rep_pre,
                                               const float* __restrict__ Wpp,
                                               const float* __restrict__ bpp,
                                               const float* __restrict__ y0a,
                                               const float* __restrict__ y1a,
                                               const float* __restrict__ b01,
                                               const float* __restrict__ b11,
                                               const int* __restrict__ t,
                                               float* __restrict__ out, int n) {
  int lane = threadIdx.x & 63;
  int i = (blockIdx.x * 256 + threadIdx.x) >> 6;
  if (i >= n) return;
  const float* r = rep_pre + (size_t)i * 128;
  float r1 = fmaxf(r[lane], 0.f);
  float r2 = fmaxf(r[lane + 64], 0.f);
  float v = r1 * Wpp[lane] + r2 * Wpp[lane + 64];
#pragma unroll
  for (int off = 32; off; off >>= 1) v += __shfl_down(v, off, 64);
  if (lane == 0) {
    float p = 1.f / (1.f + expf(-(v + bpp[0])));
    out[i] = p;
    out[n + i] = (t[i] > 0) ? (y1a[i] + b11[0]) : (y0a[i] + b01[0]);
  }
}

extern "C" void kernel_launch(void* const* d_in, const int* in_sizes, int n_in,
                              void* d_out, int out_size, void* d_ws, size_t ws_size,
                              hipStream_t stream) {
  const float* x   = (const float*)d_in[0];
  const int*   t   = (const int*)d_in[1];
  const int*   ei  = (const int*)d_in[3];
  const float* W1  = (const float*)d_in[4];
  const float* b1  = (const float*)d_in[5];
  const float* W2  = (const float*)d_in[6];
  const float* b2  = (const float*)d_in[7];
  const float* W00 = (const float*)d_in[8];
  const float* b00 = (const float*)d_in[9];
  const float* W10 = (const float*)d_in[10];
  const float* b10 = (const float*)d_in[11];
  const float* b01 = (const float*)d_in[13];
  const float* W11 = (const float*)d_in[14];
  const float* b11 = (const float*)d_in[15];
  const float* W01 = (const float*)d_in[12];
  const float* Wpp = (const float*)d_in[16];
  const float* bpp = (const float*)d_in[17];

  const int N = in_sizes[0] / 128;
  const int E = in_sizes[3] / 2;
  const int* srcp = ei;
  const int* dstp = ei + E;

  const size_t S = (size_t)N * 128 * sizeof(float);
  const int nbN = (N + 255) / 256;          // scan blocks too
  const int nbE = (E + 255) / 256;
  const int nbWaveN = (N + 3) / 4;
  dim3 gemmGrid(2, (N + 63) / 64);
  float* out = (float*)d_out;

  // workspace layout
  char* ws = (char*)d_ws;
  float* B1  = (float*)ws; ws += align256(S);
  float* B2  = (float*)ws; ws += align256(S);
  int*   deg = (int*)ws;   ws += align256((size_t)N * 4);
  float* dnv = (float*)ws; ws += align256((size_t)N * 4);
  float* y0a = (float*)ws; ws += align256((size_t)N * 4);
  float* y1a = (float*)ws; ws += align256((size_t)N * 4);
  int*   rowptr = (int*)ws; ws += align256((size_t)N * 4);
  int*   cursor = (int*)ws; ws += align256((size_t)N * 4);
  int*   blksum = (int*)ws; ws += align256((size_t)nbN * 4);
  int*   srcs   = (int*)ws; ws += align256((size_t)E * 4);
  float* nrms   = (float*)ws; ws += align256((size_t)E * 4);
  size_t need = (size_t)(ws - (char*)d_ws);

  const bool csr_ok = (need <= ws_size) && (nbN <= 1024);

  if (csr_ok) {
    // ---- CSR build (graph-only; reused for both layers) ----
    k_deg_zero<<<nbN, 256, 0, stream>>>(deg, N);
    k_deg_count<<<nbE, 256, 0, stream>>>(dstp, deg, E);
    k_dinv<<<nbN, 256, 0, stream>>>(deg, dnv, N);
    k_scan1<<<nbN, 256, 0, stream>>>(deg, rowptr, blksum, N);
    k_scan2<<<1, 1024, 0, stream>>>(blksum, nbN);
    k_scan3<<<nbN, 256, 0, stream>>>(rowptr, blksum, cursor, N);
    k_fill<<<nbE, 256, 0, stream>>>(srcp, dstp, dnv, cursor, srcs, nrms, E);

    // ---- layer 1 ----
    k_gemm<false, false><<<gemmGrid, 256, 0, stream>>>(x, W1, nullptr, B1, N);
    k_gather<<<nbWaveN, 256, 0, stream>>>(srcs, nrms, rowptr, deg, dnv, B1, b1, B2, N);
    // ---- layer 2 ----
    k_gemm<true, false><<<gemmGrid, 256, 0, stream>>>(B2, W2, nullptr, B1, N);
    k_gather<<<nbWaveN, 256, 0, stream>>>(srcs, nrms, rowptr, deg, dnv, B1, b2, B2, N);
  } else {
    // ---- fallback: atomic scatter path ----
    const int nbNode32 = (N * 32 + 255) / 256;
    const int nbWaveE = (int)(((size_t)E * 64 + 255) / 256);
    k_deg_init1<<<nbN, 256, 0, stream>>>(deg, N);
    k_deg_count<<<nbE, 256, 0, stream>>>(dstp, deg, E);
    k_dinv0<<<nbN, 256, 0, stream>>>(deg, dnv, N);
    k_gemm<false, false><<<gemmGrid, 256, 0, stream>>>(x, W1, nullptr, B1, N);
    k_selfinit<<<nbNode32, 256, 0, stream>>>(B1, dnv, b1, B2, N);
    k_scatter<<<nbWaveE, 256, 0, stream>>>(srcp, dstp, dnv, B1, B2, E);
    k_gemm<true, false><<<gemmGrid, 256, 0, stream>>>(B2, W2, nullptr, B1, N);
    k_selfinit<<<nbNode32, 256, 0, stream>>>(B1, dnv, b2, B2, N);
    k_scatter<<<nbWaveE, 256, 0, stream>>>(srcp, dstp, dnv, B1, B2, E);
  }

  // ---- heads ----
  k_gemm<true, true><<<gemmGrid, 256, 0, stream>>>(B2, W00, b00, B1, N);
  k_dot<<<nbWaveN, 256, 0, stream>>>(B1, W01, y0a, N);
  k_gemm<true, true><<<gemmGrid, 256, 0, stream>>>(B2, W10, b10, B1, N);
  k_dot<<<nbWaveN, 256, 0, stream>>>(B1, W11, y1a, N);

  k_final<<<nbWaveN, 256, 0, stream>>>(B2, Wpp, bpp, y0a, y1a, b01, b11, t, out, N);
}

// Round 5
// 795.017 us; speedup vs baseline: 3.9119x; 1.0397x over previous
//
#include <hip/hip_runtime.h>
#include <math.h>

static inline size_t align256(size_t x) { return (x + 255) & ~(size_t)255; }

// ---------------- degree ----------------
__global__ __launch_bounds__(256) void k_deg_zero(int* __restrict__ deg, int n) {
  int i = blockIdx.x * 256 + threadIdx.x;
  if (i < n) deg[i] = 0;
}

__global__ __launch_bounds__(256) void k_deg_count(const int* __restrict__ dst,
                                                   int* __restrict__ deg, int E) {
  int e = blockIdx.x * 256 + threadIdx.x;
  if (e < E) atomicAdd(&deg[dst[e]], 1);
}

// dinv = rsqrt(indeg + 1)  (self-loop)
__global__ __launch_bounds__(256) void k_dinv(const int* __restrict__ deg,
                                              float* __restrict__ dinv, int n) {
  int i = blockIdx.x * 256 + threadIdx.x;
  if (i < n) dinv[i] = rsqrtf((float)(deg[i] + 1));
}

// ---------------- exclusive scan (3 kernels) ----------------
__global__ __launch_bounds__(256) void k_scan1(const int* __restrict__ deg,
                                               int* __restrict__ excl,
                                               int* __restrict__ blksum, int n) {
  __shared__ int sm[256];
  int i = blockIdx.x * 256 + threadIdx.x;
  int v = (i < n) ? deg[i] : 0;
  sm[threadIdx.x] = v;
  __syncthreads();
  for (int off = 1; off < 256; off <<= 1) {
    int t = (threadIdx.x >= off) ? sm[threadIdx.x - off] : 0;
    __syncthreads();
    sm[threadIdx.x] += t;
    __syncthreads();
  }
  if (i < n) excl[i] = sm[threadIdx.x] - v;   // exclusive within block
  if (threadIdx.x == 255) blksum[blockIdx.x] = sm[255];
}

__global__ __launch_bounds__(1024) void k_scan2(int* __restrict__ blksum, int nb) {
  __shared__ int sm[1024];
  int v = (threadIdx.x < (unsigned)nb) ? blksum[threadIdx.x] : 0;
  sm[threadIdx.x] = v;
  __syncthreads();
  for (int off = 1; off < 1024; off <<= 1) {
    int t = (threadIdx.x >= off) ? sm[threadIdx.x - off] : 0;
    __syncthreads();
    sm[threadIdx.x] += t;
    __syncthreads();
  }
  if (threadIdx.x < (unsigned)nb) blksum[threadIdx.x] = sm[threadIdx.x] - v;  // exclusive
}

__global__ __launch_bounds__(256) void k_scan3(int* __restrict__ excl,
                                               const int* __restrict__ blksum,
                                               int* __restrict__ cursor, int n) {
  int i = blockIdx.x * 256 + threadIdx.x;
  if (i < n) {
    int r = excl[i] + blksum[blockIdx.x];
    excl[i] = r;
    cursor[i] = r;
  }
}

// ---------------- CSR fill: srcs only (norm computed in gather) ----------------
__global__ __launch_bounds__(256) void k_fill(const int* __restrict__ src,
                                              const int* __restrict__ dst,
                                              int* __restrict__ cursor,
                                              int* __restrict__ srcs, int E) {
  int e = blockIdx.x * 256 + threadIdx.x;
  if (e >= E) return;
  int s = src[e], d = dst[e];
  int pos = atomicAdd(&cursor[d], 1);
  srcs[pos] = s;
}

// ---------------- gather-aggregate: wave per dst node ----------------
// out[i] = bias + dinv[i]^2 * xw[i] + sum_j dinv[srcs_j]*dinv[i] * xw[srcs_j]
__global__ __launch_bounds__(256) void k_gather(const int* __restrict__ srcs,
                                                const int* __restrict__ rowptr,
                                                const int* __restrict__ deg,
                                                const float* __restrict__ dinv,
                                                const float* __restrict__ xw,
                                                const float* __restrict__ bias,
                                                float* __restrict__ out, int n) {
  int lane = threadIdx.x & 63;
  int i = (blockIdx.x * 256 + threadIdx.x) >> 6;
  if (i >= n) return;
  const int c = lane * 2;
  float di = dinv[i];
  const float2 self = *(const float2*)(xw + (size_t)i * 128 + c);
  const float2 bv = *(const float2*)(bias + c);
  float ax = fmaf(di * di, self.x, bv.x);
  float ay = fmaf(di * di, self.y, bv.y);

  int j = rowptr[i];
  int end = j + deg[i];
  for (; j + 4 <= end; j += 4) {
    int s0 = srcs[j], s1 = srcs[j + 1], s2i = srcs[j + 2], s3 = srcs[j + 3];
    float n0 = dinv[s0] * di, n1 = dinv[s1] * di;
    float n2 = dinv[s2i] * di, n3 = dinv[s3] * di;
    const float2 v0 = *(const float2*)(xw + (size_t)s0 * 128 + c);
    const float2 v1 = *(const float2*)(xw + (size_t)s1 * 128 + c);
    const float2 v2 = *(const float2*)(xw + (size_t)s2i * 128 + c);
    const float2 v3 = *(const float2*)(xw + (size_t)s3 * 128 + c);
    ax = fmaf(v0.x, n0, ax); ay = fmaf(v0.y, n0, ay);
    ax = fmaf(v1.x, n1, ax); ay = fmaf(v1.y, n1, ay);
    ax = fmaf(v2.x, n2, ax); ay = fmaf(v2.y, n2, ay);
    ax = fmaf(v3.x, n3, ax); ay = fmaf(v3.y, n3, ay);
  }
  for (; j < end; ++j) {
    int s = srcs[j];
    float nm = dinv[s] * di;
    const float2 v = *(const float2*)(xw + (size_t)s * 128 + c);
    ax = fmaf(v.x, nm, ax); ay = fmaf(v.y, nm, ay);
  }
  float2 o; o.x = ax; o.y = ay;
  *(float2*)(out + (size_t)i * 128 + c) = o;
}

// ---------------- legacy atomic path (fallback if ws too small) ----------------
__global__ __launch_bounds__(256) void k_deg_init1(int* __restrict__ deg, int n) {
  int i = blockIdx.x * 256 + threadIdx.x;
  if (i < n) deg[i] = 1;
}
__global__ __launch_bounds__(256) void k_dinv0(const int* __restrict__ deg,
                                               float* __restrict__ dinv, int n) {
  int i = blockIdx.x * 256 + threadIdx.x;
  if (i < n) dinv[i] = rsqrtf((float)deg[i]);
}
__global__ __launch_bounds__(256) void k_selfinit(const float* __restrict__ xw,
                                                  const float* __restrict__ dinv,
                                                  const float* __restrict__ bias,
                                                  float* __restrict__ agg, int n) {
  int idx = blockIdx.x * 256 + threadIdx.x;
  if (idx >= n * 32) return;
  int i = idx >> 5;
  int c = (idx & 31) << 2;
  float di = dinv[i];
  float s = di * di;
  const float4 v = *(const float4*)(xw + (size_t)i * 128 + c);
  const float4 b = *(const float4*)(bias + c);
  float4 o;
  o.x = fmaf(s, v.x, b.x);
  o.y = fmaf(s, v.y, b.y);
  o.z = fmaf(s, v.z, b.z);
  o.w = fmaf(s, v.w, b.w);
  *(float4*)(agg + (size_t)i * 128 + c) = o;
}
__global__ __launch_bounds__(256) void k_scatter(const int* __restrict__ src,
                                                 const int* __restrict__ dst,
                                                 const float* __restrict__ dinv,
                                                 const float* __restrict__ xw,
                                                 float* __restrict__ agg, int E) {
  int lane = threadIdx.x & 63;
  int e = (blockIdx.x * 256 + threadIdx.x) >> 6;
  if (e >= E) return;
  int s = src[e], d = dst[e];
  float nrm = dinv[s] * dinv[d];
  const float2 v = *(const float2*)(xw + (size_t)s * 128 + lane * 2);
  float* base = agg + (size_t)d * 128 + lane * 2;
  atomicAdd(base, v.x * nrm);
  atomicAdd(base + 1, v.y * nrm);
}

// ---------------- GEMM: C = (RELU_A ? relu(A) : A) @ W ----------------
template<bool RELU_A>
__global__ __launch_bounds__(256) void k_gemm(const float* __restrict__ A,
                                              const float* __restrict__ W,
                                              float* __restrict__ C, int n) {
  __shared__ float As[64][132];
  __shared__ float Ws[128][68];
  const int tid = threadIdx.x;
  const int ct = blockIdx.x;
  const size_t row0 = (size_t)blockIdx.y * 64;

  {
    int c = (tid & 15) << 2;
    int kb = tid >> 4;
#pragma unroll
    for (int p = 0; p < 8; ++p) {
      int k = kb + p * 16;
      const float4 wv = *(const float4*)(W + (size_t)k * 128 + ct * 64 + c);
      *(float4*)&Ws[k][c] = wv;
    }
  }
  {
    int c = (tid & 31) << 2;
    int rb = tid >> 5;
#pragma unroll
    for (int p = 0; p < 8; ++p) {
      int r = rb + p * 8;
      size_t gr = row0 + r;
      float4 av = make_float4(0.f, 0.f, 0.f, 0.f);
      if (gr < (size_t)n) {
        av = *(const float4*)(A + gr * 128 + c);
        if (RELU_A) {
          av.x = fmaxf(av.x, 0.f);
          av.y = fmaxf(av.y, 0.f);
          av.z = fmaxf(av.z, 0.f);
          av.w = fmaxf(av.w, 0.f);
        }
      }
      *(float4*)&As[r][c] = av;
    }
  }
  __syncthreads();

  const int tx = tid & 15, ty = tid >> 4;
  const int r0 = ty << 2, c0 = tx << 2;
  float acc[4][4] = {{0.f}};

#pragma unroll 4
  for (int k = 0; k < 128; ++k) {
    const float4 wv = *(const float4*)&Ws[k][c0];
    float a[4];
#pragma unroll
    for (int i = 0; i < 4; ++i) a[i] = As[r0 + i][k];
#pragma unroll
    for (int i = 0; i < 4; ++i) {
      acc[i][0] = fmaf(a[i], wv.x, acc[i][0]);
      acc[i][1] = fmaf(a[i], wv.y, acc[i][1]);
      acc[i][2] = fmaf(a[i], wv.z, acc[i][2]);
      acc[i][3] = fmaf(a[i], wv.w, acc[i][3]);
    }
  }

#pragma unroll
  for (int i = 0; i < 4; ++i) {
    size_t gr = row0 + r0 + i;
    if (gr < (size_t)n) {
      float4 o;
      o.x = acc[i][0]; o.y = acc[i][1]; o.z = acc[i][2]; o.w = acc[i][3];
      *(float4*)(C + gr * 128 + ct * 64 + c0) = o;
    }
  }
}

// ---------------- fused heads: p1 + y in one pass over rep ----------------
// rep = relu(B2). p1 = sigmoid(rep@Wpp+bpp).
// y0 = relu(rep@W00+b00)@W01 ; y1 = relu(rep@W10+b10)@W11 ; y = t ? y1+b11 : y0+b01.
__global__ __launch_bounds__(256) void k_heads(const float* __restrict__ rep_pre,
                                               const float* __restrict__ W00,
                                               const float* __restrict__ b00,
                                               const float* __restrict__ W10,
                                               const float* __restrict__ b10,
                                               const float* __restrict__ W01,
                                               const float* __restrict__ b01,
                                               const float* __restrict__ W11,
                                               const float* __restrict__ b11,
                                               const float* __restrict__ Wpp,
                                               const float* __restrict__ bpp,
                                               const int* __restrict__ t,
                                               float* __restrict__ out, int n) {
  __shared__ float As[64][132];
  __shared__ float Ws[128][68];
  const int tid = threadIdx.x;
  const size_t row0 = (size_t)blockIdx.x * 64;

  // stage relu(rep) tile
  {
    int c = (tid & 31) << 2;
    int rb = tid >> 5;
#pragma unroll
    for (int p = 0; p < 8; ++p) {
      int r = rb + p * 8;
      size_t gr = row0 + r;
      float4 av = make_float4(0.f, 0.f, 0.f, 0.f);
      if (gr < (size_t)n) {
        av = *(const float4*)(rep_pre + gr * 128 + c);
        av.x = fmaxf(av.x, 0.f);
        av.y = fmaxf(av.y, 0.f);
        av.z = fmaxf(av.z, 0.f);
        av.w = fmaxf(av.w, 0.f);
      }
      *(float4*)&As[r][c] = av;
    }
  }
  __syncthreads();

  // ---- p1: each group of 4 threads handles one row (32 k each) ----
  {
    int r = tid >> 2;
    int ko = (tid & 3) * 32;
    float v = 0.f;
#pragma unroll 8
    for (int kk = 0; kk < 32; ++kk) v = fmaf(As[r][ko + kk], Wpp[ko + kk], v);
    v += __shfl_xor(v, 1, 64);
    v += __shfl_xor(v, 2, 64);
    if ((tid & 3) == 0) {
      size_t gr = row0 + r;
      if (gr < (size_t)n) out[gr] = 1.f / (1.f + expf(-(v + bpp[0])));
    }
  }

  const int tx = tid & 15, ty = tid >> 4;
  const int r0 = ty << 2, c0 = tx << 2;
  float yv[2][4];

#pragma unroll
  for (int h = 0; h < 2; ++h) {
    const float* W  = h ? W10 : W00;
    const float* bb = h ? b10 : b00;
    const float* w2 = h ? W11 : W01;
    float part[4] = {0.f, 0.f, 0.f, 0.f};

    for (int half = 0; half < 2; ++half) {
      __syncthreads();   // protect Ws reuse
      {
        int c = (tid & 15) << 2;
        int kb = tid >> 4;
#pragma unroll
        for (int p = 0; p < 8; ++p) {
          int k = kb + p * 16;
          const float4 wv = *(const float4*)(W + (size_t)k * 128 + half * 64 + c);
          *(float4*)&Ws[k][c] = wv;
        }
      }
      __syncthreads();

      float acc[4][4] = {{0.f}};
#pragma unroll 4
      for (int k = 0; k < 128; ++k) {
        const float4 wv = *(const float4*)&Ws[k][c0];
        float a[4];
#pragma unroll
        for (int i = 0; i < 4; ++i) a[i] = As[r0 + i][k];
#pragma unroll
        for (int i = 0; i < 4; ++i) {
          acc[i][0] = fmaf(a[i], wv.x, acc[i][0]);
          acc[i][1] = fmaf(a[i], wv.y, acc[i][1]);
          acc[i][2] = fmaf(a[i], wv.z, acc[i][2]);
          acc[i][3] = fmaf(a[i], wv.w, acc[i][3]);
        }
      }
      const float4 bv = *(const float4*)(bb + half * 64 + c0);
      const float4 w2v = *(const float4*)(w2 + half * 64 + c0);
#pragma unroll
      for (int i = 0; i < 4; ++i) {
        part[i] = fmaf(fmaxf(acc[i][0] + bv.x, 0.f), w2v.x, part[i]);
        part[i] = fmaf(fmaxf(acc[i][1] + bv.y, 0.f), w2v.y, part[i]);
        part[i] = fmaf(fmaxf(acc[i][2] + bv.z, 0.f), w2v.z, part[i]);
        part[i] = fmaf(fmaxf(acc[i][3] + bv.w, 0.f), w2v.w, part[i]);
      }
    }
    // reduce across tx (lanes xor 1,2,4,8 stay within same ty group)
#pragma unroll
    for (int i = 0; i < 4; ++i) {
      float v = part[i];
      v += __shfl_xor(v, 1, 64);
      v += __shfl_xor(v, 2, 64);
      v += __shfl_xor(v, 4, 64);
      v += __shfl_xor(v, 8, 64);
      yv[h][i] = v;
    }
  }

  if (tx == 0) {
#pragma unroll
    for (int i = 0; i < 4; ++i) {
      size_t gr = row0 + r0 + i;
      if (gr < (size_t)n) {
        float v = (t[gr] > 0) ? (yv[1][i] + b11[0]) : (yv[0][i] + b01[0]);
        out[n + gr] = v;
      }
    }
  }
}

extern "C" void kernel_launch(void* const* d_in, const int* in_sizes, int n_in,
                              void* d_out, int out_size, void* d_ws, size_t ws_size,
                              hipStream_t stream) {
  const float* x   = (const float*)d_in[0];
  const int*   t   = (const int*)d_in[1];
  const int*   ei  = (const int*)d_in[3];
  const float* W1  = (const float*)d_in[4];
  const float* b1  = (const float*)d_in[5];
  const float* W2  = (const float*)d_in[6];
  const float* b2  = (const float*)d_in[7];
  const float* W00 = (const float*)d_in[8];
  const float* b00 = (const float*)d_in[9];
  const float* W10 = (const float*)d_in[10];
  const float* b10 = (const float*)d_in[11];
  const float* W01 = (const float*)d_in[12];
  const float* b01 = (const float*)d_in[13];
  const float* W11 = (const float*)d_in[14];
  const float* b11 = (const float*)d_in[15];
  const float* Wpp = (const float*)d_in[16];
  const float* bpp = (const float*)d_in[17];

  const int N = in_sizes[0] / 128;
  const int E = in_sizes[3] / 2;
  const int* srcp = ei;
  const int* dstp = ei + E;

  const size_t S = (size_t)N * 128 * sizeof(float);
  const int nbN = (N + 255) / 256;
  const int nbE = (E + 255) / 256;
  const int nbWaveN = (N + 3) / 4;
  const int nbRow64 = (N + 63) / 64;
  dim3 gemmGrid(2, nbRow64);
  float* out = (float*)d_out;

  // workspace layout
  char* ws = (char*)d_ws;
  float* B1  = (float*)ws; ws += align256(S);
  float* B2  = (float*)ws; ws += align256(S);
  int*   deg = (int*)ws;   ws += align256((size_t)N * 4);
  float* dnv = (float*)ws; ws += align256((size_t)N * 4);
  int*   rowptr = (int*)ws; ws += align256((size_t)N * 4);
  int*   cursor = (int*)ws; ws += align256((size_t)N * 4);
  int*   blksum = (int*)ws; ws += align256((size_t)nbN * 4);
  int*   srcs   = (int*)ws; ws += align256((size_t)E * 4);
  size_t need = (size_t)(ws - (char*)d_ws);

  const bool csr_ok = (need <= ws_size) && (nbN <= 1024);

  if (csr_ok) {
    // ---- CSR build (graph-only; reused for both layers) ----
    k_deg_zero<<<nbN, 256, 0, stream>>>(deg, N);
    k_deg_count<<<nbE, 256, 0, stream>>>(dstp, deg, E);
    k_dinv<<<nbN, 256, 0, stream>>>(deg, dnv, N);
    k_scan1<<<nbN, 256, 0, stream>>>(deg, rowptr, blksum, N);
    k_scan2<<<1, 1024, 0, stream>>>(blksum, nbN);
    k_scan3<<<nbN, 256, 0, stream>>>(rowptr, blksum, cursor, N);
    k_fill<<<nbE, 256, 0, stream>>>(srcp, dstp, cursor, srcs, E);

    // ---- layer 1 ----
    k_gemm<false><<<gemmGrid, 256, 0, stream>>>(x, W1, B1, N);
    k_gather<<<nbWaveN, 256, 0, stream>>>(srcs, rowptr, deg, dnv, B1, b1, B2, N);
    // ---- layer 2 ----
    k_gemm<true><<<gemmGrid, 256, 0, stream>>>(B2, W2, B1, N);
    k_gather<<<nbWaveN, 256, 0, stream>>>(srcs, rowptr, deg, dnv, B1, b2, B2, N);
  } else {
    // ---- fallback: atomic scatter path ----
    const int nbNode32 = (N * 32 + 255) / 256;
    const int nbWaveE = (int)(((size_t)E * 64 + 255) / 256);
    k_deg_init1<<<nbN, 256, 0, stream>>>(deg, N);
    k_deg_count<<<nbE, 256, 0, stream>>>(dstp, deg, E);
    k_dinv0<<<nbN, 256, 0, stream>>>(deg, dnv, N);
    k_gemm<false><<<gemmGrid, 256, 0, stream>>>(x, W1, B1, N);
    k_selfinit<<<nbNode32, 256, 0, stream>>>(B1, dnv, b1, B2, N);
    k_scatter<<<nbWaveE, 256, 0, stream>>>(srcp, dstp, dnv, B1, B2, E);
    k_gemm<true><<<gemmGrid, 256, 0, stream>>>(B2, W2, B1, N);
    k_selfinit<<<nbNode32, 256, 0, stream>>>(B1, dnv, b2, B2, N);
    k_scatter<<<nbWaveE, 256, 0, stream>>>(srcp, dstp, dnv, B1, B2, E);
  }

  // ---- fused heads + final ----
  k_heads<<<nbRow64, 256, 0, stream>>>(B2, W00, b00, W10, b10, W01, b01,
                                       W11, b11, Wpp, bpp, t, out, N);
}

// Round 7
// 634.146 us; speedup vs baseline: 4.9042x; 1.2537x over previous
//
#include <hip/hip_runtime.h>
#include <math.h>

static inline size_t align256(size_t x) { return (x + 255) & ~(size_t)255; }

#define NBLK 256    // edge partition chunks (and scan width)
#define NBUCK 256   // dst buckets: bucket = dst >> 9 (512 dsts/bucket, needs N <= 131072)

// ---------------- F1: per-chunk histogram over dst buckets ----------------
__global__ __launch_bounds__(512) void k_hist(const int* __restrict__ dst,
                                              int* __restrict__ H, int E) {
  __shared__ int h[NBUCK];
  for (int i = threadIdx.x; i < NBUCK; i += 512) h[i] = 0;
  __syncthreads();
  const int C = (E + NBLK - 1) / NBLK;
  const int lo = blockIdx.x * C, hi = min(E, lo + C);
  for (int e = lo + threadIdx.x; e < hi; e += 512)
    atomicAdd(&h[dst[e] >> 9], 1);
  __syncthreads();
  for (int i = threadIdx.x; i < NBUCK; i += 512)
    H[(size_t)blockIdx.x * NBUCK + i] = h[i];
}

// ---------------- F2a: per-bucket exclusive scan over chunks ----------------
__global__ __launch_bounds__(NBLK) void k_bscan(int* __restrict__ H,
                                                int* __restrict__ bsum) {
  __shared__ int sm[NBLK];
  const int b = blockIdx.x;
  int v = H[(size_t)threadIdx.x * NBUCK + b];
  sm[threadIdx.x] = v;
  __syncthreads();
  for (int off = 1; off < NBLK; off <<= 1) {
    int t = (threadIdx.x >= off) ? sm[threadIdx.x - off] : 0;
    __syncthreads();
    sm[threadIdx.x] += t;
    __syncthreads();
  }
  H[(size_t)threadIdx.x * NBUCK + b] = sm[threadIdx.x] - v;  // exclusive over chunks
  if (threadIdx.x == NBLK - 1) bsum[b] = sm[NBLK - 1];
}

// ---------------- F2b: exclusive scan of bucket totals (+ sentinel) ----------------
__global__ __launch_bounds__(NBUCK) void k_bstart(int* __restrict__ bsum, int E) {
  __shared__ int sm[NBUCK];
  int v = bsum[threadIdx.x];
  sm[threadIdx.x] = v;
  __syncthreads();
  for (int off = 1; off < NBUCK; off <<= 1) {
    int t = (threadIdx.x >= off) ? sm[threadIdx.x - off] : 0;
    __syncthreads();
    sm[threadIdx.x] += t;
    __syncthreads();
  }
  bsum[threadIdx.x] = sm[threadIdx.x] - v;
  if (threadIdx.x == NBUCK - 1) bsum[NBUCK] = E;  // sentinel
}

// ---------------- F3: partition edges into bucket regions (packed 4B) ----------------
__global__ __launch_bounds__(512) void k_part(const int* __restrict__ src,
                                              const int* __restrict__ dst,
                                              const int* __restrict__ H,
                                              const int* __restrict__ bstart,
                                              unsigned int* __restrict__ P, int E) {
  __shared__ int cur[NBUCK];
  for (int i = threadIdx.x; i < NBUCK; i += 512)
    cur[i] = bstart[i] + H[(size_t)blockIdx.x * NBUCK + i];
  __syncthreads();
  const int C = (E + NBLK - 1) / NBLK;
  const int lo = blockIdx.x * C, hi = min(E, lo + C);
  for (int e = lo + threadIdx.x; e < hi; e += 512) {
    int d = dst[e], s = src[e];
    int pos = atomicAdd(&cur[d >> 9], 1);
    P[pos] = ((unsigned)(d & 511) << 17) | (unsigned)s;  // needs src < 2^17
  }
}

// ---------------- F4: per-bucket local sort -> srcs + rowptr + deg + dinv ----------------
__global__ __launch_bounds__(512) void k_bucket(const unsigned int* __restrict__ P,
                                                const int* __restrict__ bstart,
                                                int* __restrict__ srcs,
                                                int* __restrict__ rowptr,
                                                int* __restrict__ deg,
                                                float* __restrict__ dinv,
                                                int n) {
  __shared__ int cnt[512], scn[512], cur[512];
  const int b = blockIdx.x;
  const int base = bstart[b], endp = bstart[b + 1];
  cnt[threadIdx.x] = 0;
  __syncthreads();
  for (int e = base + threadIdx.x; e < endp; e += 512)
    atomicAdd(&cnt[P[e] >> 17], 1);
  __syncthreads();
  int v = cnt[threadIdx.x];
  scn[threadIdx.x] = v;
  __syncthreads();
  for (int off = 1; off < 512; off <<= 1) {
    int t = (threadIdx.x >= off) ? scn[threadIdx.x - off] : 0;
    __syncthreads();
    scn[threadIdx.x] += t;
    __syncthreads();
  }
  const int ex = scn[threadIdx.x] - v;   // exclusive within bucket
  cur[threadIdx.x] = ex;
  const int d = (b << 9) + threadIdx.x;
  if (d < n) {
    rowptr[d] = base + ex;
    deg[d] = v;
    dinv[d] = rsqrtf((float)(v + 1));    // +1 self-loop
  }
  __syncthreads();
  for (int e = base + threadIdx.x; e < endp; e += 512) {
    unsigned p = P[e];
    int pos = base + atomicAdd(&cur[p >> 17], 1);
    srcs[pos] = (int)(p & 0x1FFFFu);
  }
}

// ---------------- gather-aggregate: wave per dst node ----------------
// out[i] = bias + dinv[i]^2 * xw[i] + sum_j dinv[srcs_j]*dinv[i] * xw[srcs_j]
__global__ __launch_bounds__(256) void k_gather(const int* __restrict__ srcs,
                                                const int* __restrict__ rowptr,
                                                const int* __restrict__ deg,
                                                const float* __restrict__ dinv,
                                                const float* __restrict__ xw,
                                                const float* __restrict__ bias,
                                                float* __restrict__ out, int n) {
  int lane = threadIdx.x & 63;
  int i = (blockIdx.x * 256 + threadIdx.x) >> 6;
  if (i >= n) return;
  const int c = lane * 2;
  float di = dinv[i];
  const float2 self = *(const float2*)(xw + (size_t)i * 128 + c);
  const float2 bv = *(const float2*)(bias + c);
  float ax = fmaf(di * di, self.x, bv.x);
  float ay = fmaf(di * di, self.y, bv.y);

  int j = rowptr[i];
  int end = j + deg[i];
  for (; j + 4 <= end; j += 4) {
    int s0 = srcs[j], s1 = srcs[j + 1], s2i = srcs[j + 2], s3 = srcs[j + 3];
    float n0 = dinv[s0] * di, n1 = dinv[s1] * di;
    float n2 = dinv[s2i] * di, n3 = dinv[s3] * di;
    const float2 v0 = *(const float2*)(xw + (size_t)s0 * 128 + c);
    const float2 v1 = *(const float2*)(xw + (size_t)s1 * 128 + c);
    const float2 v2 = *(const float2*)(xw + (size_t)s2i * 128 + c);
    const float2 v3 = *(const float2*)(xw + (size_t)s3 * 128 + c);
    ax = fmaf(v0.x, n0, ax); ay = fmaf(v0.y, n0, ay);
    ax = fmaf(v1.x, n1, ax); ay = fmaf(v1.y, n1, ay);
    ax = fmaf(v2.x, n2, ax); ay = fmaf(v2.y, n2, ay);
    ax = fmaf(v3.x, n3, ax); ay = fmaf(v3.y, n3, ay);
  }
  for (; j < end; ++j) {
    int s = srcs[j];
    float nm = dinv[s] * di;
    const float2 v = *(const float2*)(xw + (size_t)s * 128 + c);
    ax = fmaf(v.x, nm, ax); ay = fmaf(v.y, nm, ay);
  }
  float2 o; o.x = ax; o.y = ay;
  *(float2*)(out + (size_t)i * 128 + c) = o;
}

// ---------------- legacy atomic path (fallback) ----------------
__global__ __launch_bounds__(256) void k_deg_init1(int* __restrict__ deg, int n) {
  int i = blockIdx.x * 256 + threadIdx.x;
  if (i < n) deg[i] = 1;
}
__global__ __launch_bounds__(256) void k_deg_count(const int* __restrict__ dst,
                                                   int* __restrict__ deg, int E) {
  int e = blockIdx.x * 256 + threadIdx.x;
  if (e < E) atomicAdd(&deg[dst[e]], 1);
}
__global__ __launch_bounds__(256) void k_dinv0(const int* __restrict__ deg,
                                               float* __restrict__ dinv, int n) {
  int i = blockIdx.x * 256 + threadIdx.x;
  if (i < n) dinv[i] = rsqrtf((float)deg[i]);
}
__global__ __launch_bounds__(256) void k_selfinit(const float* __restrict__ xw,
                                                  const float* __restrict__ dinv,
                                                  const float* __restrict__ bias,
                                                  float* __restrict__ agg, int n) {
  int idx = blockIdx.x * 256 + threadIdx.x;
  if (idx >= n * 32) return;
  int i = idx >> 5;
  int c = (idx & 31) << 2;
  float di = dinv[i];
  float s = di * di;
  const float4 v = *(const float4*)(xw + (size_t)i * 128 + c);
  const float4 b = *(const float4*)(bias + c);
  float4 o;
  o.x = fmaf(s, v.x, b.x);
  o.y = fmaf(s, v.y, b.y);
  o.z = fmaf(s, v.z, b.z);
  o.w = fmaf(s, v.w, b.w);
  *(float4*)(agg + (size_t)i * 128 + c) = o;
}
__global__ __launch_bounds__(256) void k_scatter(const int* __restrict__ src,
                                                 const int* __restrict__ dst,
                                                 const float* __restrict__ dinv,
                                                 const float* __restrict__ xw,
                                                 float* __restrict__ agg, int E) {
  int lane = threadIdx.x & 63;
  int e = (blockIdx.x * 256 + threadIdx.x) >> 6;
  if (e >= E) return;
  int s = src[e], d = dst[e];
  float nrm = dinv[s] * dinv[d];
  const float2 v = *(const float2*)(xw + (size_t)s * 128 + lane * 2);
  float* base = agg + (size_t)d * 128 + lane * 2;
  atomicAdd(base, v.x * nrm);
  atomicAdd(base + 1, v.y * nrm);
}

// ---------------- GEMM: C = (RELU_A ? relu(A) : A) @ W ----------------
template<bool RELU_A>
__global__ __launch_bounds__(256) void k_gemm(const float* __restrict__ A,
                                              const float* __restrict__ W,
                                              float* __restrict__ C, int n) {
  __shared__ float As[64][132];
  __shared__ float Ws[128][68];
  const int tid = threadIdx.x;
  const int ct = blockIdx.x;
  const size_t row0 = (size_t)blockIdx.y * 64;

  {
    int c = (tid & 15) << 2;
    int kb = tid >> 4;
#pragma unroll
    for (int p = 0; p < 8; ++p) {
      int k = kb + p * 16;
      const float4 wv = *(const float4*)(W + (size_t)k * 128 + ct * 64 + c);
      *(float4*)&Ws[k][c] = wv;
    }
  }
  {
    int c = (tid & 31) << 2;
    int rb = tid >> 5;
#pragma unroll
    for (int p = 0; p < 8; ++p) {
      int r = rb + p * 8;
      size_t gr = row0 + r;
      float4 av = make_float4(0.f, 0.f, 0.f, 0.f);
      if (gr < (size_t)n) {
        av = *(const float4*)(A + gr * 128 + c);
        if (RELU_A) {
          av.x = fmaxf(av.x, 0.f);
          av.y = fmaxf(av.y, 0.f);
          av.z = fmaxf(av.z, 0.f);
          av.w = fmaxf(av.w, 0.f);
        }
      }
      *(float4*)&As[r][c] = av;
    }
  }
  __syncthreads();

  const int tx = tid & 15, ty = tid >> 4;
  const int r0 = ty << 2, c0 = tx << 2;
  float acc[4][4] = {{0.f}};

#pragma unroll 4
  for (int k = 0; k < 128; ++k) {
    const float4 wv = *(const float4*)&Ws[k][c0];
    float a[4];
#pragma unroll
    for (int i = 0; i < 4; ++i) a[i] = As[r0 + i][k];
#pragma unroll
    for (int i = 0; i < 4; ++i) {
      acc[i][0] = fmaf(a[i], wv.x, acc[i][0]);
      acc[i][1] = fmaf(a[i], wv.y, acc[i][1]);
      acc[i][2] = fmaf(a[i], wv.z, acc[i][2]);
      acc[i][3] = fmaf(a[i], wv.w, acc[i][3]);
    }
  }

#pragma unroll
  for (int i = 0; i < 4; ++i) {
    size_t gr = row0 + r0 + i;
    if (gr < (size_t)n) {
      float4 o;
      o.x = acc[i][0]; o.y = acc[i][1]; o.z = acc[i][2]; o.w = acc[i][3];
      *(float4*)(C + gr * 128 + ct * 64 + c0) = o;
    }
  }
}

// ---------------- fused heads: p1 + y in one pass over rep ----------------
__global__ __launch_bounds__(256) void k_heads(const float* __restrict__ rep_pre,
                                               const float* __restrict__ W00,
                                               const float* __restrict__ b00,
                                               const float* __restrict__ W10,
                                               const float* __restrict__ b10,
                                               const float* __restrict__ W01,
                                               const float* __restrict__ b01,
                                               const float* __restrict__ W11,
                                               const float* __restrict__ b11,
                                               const float* __restrict__ Wpp,
                                               const float* __restrict__ bpp,
                                               const int* __restrict__ t,
                                               float* __restrict__ out, int n) {
  __shared__ float As[64][132];
  __shared__ float Ws[128][68];
  const int tid = threadIdx.x;
  const size_t row0 = (size_t)blockIdx.x * 64;

  {
    int c = (tid & 31) << 2;
    int rb = tid >> 5;
#pragma unroll
    for (int p = 0; p < 8; ++p) {
      int r = rb + p * 8;
      size_t gr = row0 + r;
      float4 av = make_float4(0.f, 0.f, 0.f, 0.f);
      if (gr < (size_t)n) {
        av = *(const float4*)(rep_pre + gr * 128 + c);
        av.x = fmaxf(av.x, 0.f);
        av.y = fmaxf(av.y, 0.f);
        av.z = fmaxf(av.z, 0.f);
        av.w = fmaxf(av.w, 0.f);
      }
      *(float4*)&As[r][c] = av;
    }
  }
  __syncthreads();

  // p1: 4 threads per row
  {
    int r = tid >> 2;
    int ko = (tid & 3) * 32;
    float v = 0.f;
#pragma unroll 8
    for (int kk = 0; kk < 32; ++kk) v = fmaf(As[r][ko + kk], Wpp[ko + kk], v);
    v += __shfl_xor(v, 1, 64);
    v += __shfl_xor(v, 2, 64);
    if ((tid & 3) == 0) {
      size_t gr = row0 + r;
      if (gr < (size_t)n) out[gr] = 1.f / (1.f + expf(-(v + bpp[0])));
    }
  }

  const int tx = tid & 15, ty = tid >> 4;
  const int r0 = ty << 2, c0 = tx << 2;
  float yv[2][4];

#pragma unroll
  for (int h = 0; h < 2; ++h) {
    const float* W  = h ? W10 : W00;
    const float* bb = h ? b10 : b00;
    const float* w2 = h ? W11 : W01;
    float part[4] = {0.f, 0.f, 0.f, 0.f};

    for (int half = 0; half < 2; ++half) {
      __syncthreads();
      {
        int c = (tid & 15) << 2;
        int kb = tid >> 4;
#pragma unroll
        for (int p = 0; p < 8; ++p) {
          int k = kb + p * 16;
          const float4 wv = *(const float4*)(W + (size_t)k * 128 + half * 64 + c);
          *(float4*)&Ws[k][c] = wv;
        }
      }
      __syncthreads();

      float acc[4][4] = {{0.f}};
#pragma unroll 4
      for (int k = 0; k < 128; ++k) {
        const float4 wv = *(const float4*)&Ws[k][c0];
        float a[4];
#pragma unroll
        for (int i = 0; i < 4; ++i) a[i] = As[r0 + i][k];
#pragma unroll
        for (int i = 0; i < 4; ++i) {
          acc[i][0] = fmaf(a[i], wv.x, acc[i][0]);
          acc[i][1] = fmaf(a[i], wv.y, acc[i][1]);
          acc[i][2] = fmaf(a[i], wv.z, acc[i][2]);
          acc[i][3] = fmaf(a[i], wv.w, acc[i][3]);
        }
      }
      const float4 bv = *(const float4*)(bb + half * 64 + c0);
      const float4 w2v = *(const float4*)(w2 + half * 64 + c0);
#pragma unroll
      for (int i = 0; i < 4; ++i) {
        part[i] = fmaf(fmaxf(acc[i][0] + bv.x, 0.f), w2v.x, part[i]);
        part[i] = fmaf(fmaxf(acc[i][1] + bv.y, 0.f), w2v.y, part[i]);
        part[i] = fmaf(fmaxf(acc[i][2] + bv.z, 0.f), w2v.z, part[i]);
        part[i] = fmaf(fmaxf(acc[i][3] + bv.w, 0.f), w2v.w, part[i]);
      }
    }
#pragma unroll
    for (int i = 0; i < 4; ++i) {
      float v = part[i];
      v += __shfl_xor(v, 1, 64);
      v += __shfl_xor(v, 2, 64);
      v += __shfl_xor(v, 4, 64);
      v += __shfl_xor(v, 8, 64);
      yv[h][i] = v;
    }
  }

  if (tx == 0) {
#pragma unroll
    for (int i = 0; i < 4; ++i) {
      size_t gr = row0 + r0 + i;
      if (gr < (size_t)n) {
        float v = (t[gr] > 0) ? (yv[1][i] + b11[0]) : (yv[0][i] + b01[0]);
        out[n + gr] = v;
      }
    }
  }
}

extern "C" void kernel_launch(void* const* d_in, const int* in_sizes, int n_in,
                              void* d_out, int out_size, void* d_ws, size_t ws_size,
                              hipStream_t stream) {
  const float* x   = (const float*)d_in[0];
  const int*   t   = (const int*)d_in[1];
  const int*   ei  = (const int*)d_in[3];
  const float* W1  = (const float*)d_in[4];
  const float* b1  = (const float*)d_in[5];
  const float* W2  = (const float*)d_in[6];
  const float* b2  = (const float*)d_in[7];
  const float* W00 = (const float*)d_in[8];
  const float* b00 = (const float*)d_in[9];
  const float* W10 = (const float*)d_in[10];
  const float* b10 = (const float*)d_in[11];
  const float* W01 = (const float*)d_in[12];
  const float* b01 = (const float*)d_in[13];
  const float* W11 = (const float*)d_in[14];
  const float* b11 = (const float*)d_in[15];
  const float* Wpp = (const float*)d_in[16];
  const float* bpp = (const float*)d_in[17];

  const int N = in_sizes[0] / 128;
  const int E = in_sizes[3] / 2;
  const int* srcp = ei;
  const int* dstp = ei + E;

  const size_t S = (size_t)N * 128 * sizeof(float);
  const int nbN = (N + 255) / 256;
  const int nbE = (E + 255) / 256;
  const int nbWaveN = (N + 3) / 4;
  const int nbRow64 = (N + 63) / 64;
  dim3 gemmGrid(2, nbRow64);
  float* out = (float*)d_out;

  // workspace layout
  char* ws = (char*)d_ws;
  float* B1  = (float*)ws; ws += align256(S);
  float* B2  = (float*)ws; ws += align256(S);
  int*   deg = (int*)ws;   ws += align256((size_t)N * 4);
  float* dnv = (float*)ws; ws += align256((size_t)N * 4);
  int*   rowptr = (int*)ws; ws += align256((size_t)N * 4);
  int*   H      = (int*)ws; ws += align256((size_t)NBLK * NBUCK * 4);
  int*   bstart = (int*)ws; ws += align256((size_t)(NBUCK + 1) * 4);
  unsigned int* P = (unsigned int*)ws; ws += align256((size_t)E * 4);
  int*   srcs   = (int*)ws; ws += align256((size_t)E * 4);
  size_t need = (size_t)(ws - (char*)d_ws);

  // bucket sort requires: ws fits, dst < NBUCK*512, src < 2^17
  const bool csr_ok = (need <= ws_size) && (N <= NBUCK * 512) && (N <= (1 << 17));

  if (csr_ok) {
    // ---- CSR build via two-level bucket sort (no global atomics) ----
    k_hist  <<<NBLK, 512, 0, stream>>>(dstp, H, E);
    k_bscan <<<NBUCK, NBLK, 0, stream>>>(H, bstart);
    k_bstart<<<1, NBUCK, 0, stream>>>(bstart, E);
    k_part  <<<NBLK, 512, 0, stream>>>(srcp, dstp, H, bstart, P, E);
    k_bucket<<<NBUCK, 512, 0, stream>>>(P, bstart, srcs, rowptr, deg, dnv, N);

    // ---- layer 1 ----
    k_gemm<false><<<gemmGrid, 256, 0, stream>>>(x, W1, B1, N);
    k_gather<<<nbWaveN, 256, 0, stream>>>(srcs, rowptr, deg, dnv, B1, b1, B2, N);
    // ---- layer 2 ----
    k_gemm<true><<<gemmGrid, 256, 0, stream>>>(B2, W2, B1, N);
    k_gather<<<nbWaveN, 256, 0, stream>>>(srcs, rowptr, deg, dnv, B1, b2, B2, N);
  } else {
    // ---- fallback: atomic scatter path ----
    const int nbNode32 = (N * 32 + 255) / 256;
    const int nbWaveE = (int)(((size_t)E * 64 + 255) / 256);
    k_deg_init1<<<nbN, 256, 0, stream>>>(deg, N);
    k_deg_count<<<nbE, 256, 0, stream>>>(dstp, deg, E);
    k_dinv0<<<nbN, 256, 0, stream>>>(deg, dnv, N);
    k_gemm<false><<<gemmGrid, 256, 0, stream>>>(x, W1, B1, N);
    k_selfinit<<<nbNode32, 256, 0, stream>>>(B1, dnv, b1, B2, N);
    k_scatter<<<nbWaveE, 256, 0, stream>>>(srcp, dstp, dnv, B1, B2, E);
    k_gemm<true><<<gemmGrid, 256, 0, stream>>>(B2, W2, B1, N);
    k_selfinit<<<nbNode32, 256, 0, stream>>>(B1, dnv, b2, B2, N);
    k_scatter<<<nbWaveE, 256, 0, stream>>>(srcp, dstp, dnv, B1, B2, E);
  }

  // ---- fused heads + final ----
  k_heads<<<nbRow64, 256, 0, stream>>>(B2, W00, b00, W10, b10, W01, b01,
                                       W11, b11, Wpp, bpp, t, out, N);
}